// Round 7
// baseline (2874.029 us; speedup 1.0000x reference)
//
#include <hip/hip_runtime.h>
#include <math.h>

// Conv1D(k=2,F=64,relu) -> LSTM1(H=100, relu cell, seq) -> LSTM2 (last) ->
// Dense(3) -> softmax.  B=128, T=2048, T'=2047.
//
// Round-12 = r9 structure (1024 thr, 4 waves/SIMD, 4-way splits; correctness
// proven in its passing run) + r11 packed-f16 weights (spill elimination
// proven: WRITE_SIZE 15.7MB -> 5KB).  r9's 35MB spill was the branchy f32
// gather, not steady state: per-thread steady need is producer 96 h2 + ~30,
// consumer 100 h2 + ~30 ~= 126-130 of the 128-reg/wave (unified V+A) budget
// at 16 waves/CU.  Packed loads keep init pressure flat.
//  * producer 400 thr: (unit p = rt>>2, K-quarter sq = rt&3) over K1=192
//    [x(64); h1(100); pad(28)], quarter = 48 halves = 24 h2 x 4 gates.
//    qsum4 quad reduction (DPP 0xB1 + 0x4E).
//  * consumer 400 thr: (unit p, gate-pair g2, K-half kh) over K2=208
//    [x2(100); pad4; h2(100); pad4]; 50 h2 x 2 gates (no pad weights:
//    12 float4 dots + float2 tail).  psum2 (xor-1) over kh, xswap2 (xor-2)
//    gate-pair exchange; lane (rt&3)==0 writes h.
//  * conv wave (64 thr, 1 filter each) feeds the X1 ring; wave 15 barriers.
//  * 2-slot LDS rings, 1 barrier/step, producer 1 step ahead of consumer.
//  TLP rationale: r11 step = 2730 cy with ~770 cy VALU/SIMD + ~900 cy DS/CU
//  -> >=1000 cy is stall with only 2 phase-locked waves/SIMD.  4 waves/SIMD
//  halves per-wave serial work and doubles stall overlap.

typedef _Float16 h2 __attribute__((ext_vector_type(2)));

#define BB 128
#define TT 2048
#define TP 2047
#define HH 100
#define G4 400
#define FF 64

#define K1 192   // producer operand halves: [x(64) ; h1(100) ; pad(28)]
#define K2 208   // consumer operand halves: [x2(100); pad4 ; h2(100); pad4]

#define NPH2 (400 * 96)    // producer packed h2 (400 thr x 24 pairs x 4 gates)
#define NCH2 (400 * 100)   // consumer packed h2 (400 thr x 50 pairs x 2 gates)

#define L24(X) X(0) X(1) X(2) X(3) X(4) X(5) X(6) X(7) X(8) X(9) \
 X(10) X(11) X(12) X(13) X(14) X(15) X(16) X(17) X(18) X(19) \
 X(20) X(21) X(22) X(23)
#define L50(X) L24(X) X(24) X(25) X(26) X(27) X(28) X(29) \
 X(30) X(31) X(32) X(33) X(34) X(35) X(36) X(37) X(38) X(39) \
 X(40) X(41) X(42) X(43) X(44) X(45) X(46) X(47) X(48) X(49)

#define FD(w, x, acc) acc = __builtin_amdgcn_fdot2(w, x, acc, false)
#define B2(f) __builtin_bit_cast(h2, f)

// ---------------- producer weight machinery (96 h2 / thread) ---------------
#define PDW(i) h2 pa##i, pb##i, pc##i, pd##i;
#define LWPK(i) { const float4 v = gwp[i]; \
  pa##i = B2(v.x); pb##i = B2(v.y); pc##i = B2(v.z); pd##i = B2(v.w); }

// one float4 operand chunk feeds 4 gates (8 chains via element parity)
#define DOTP(r, i0, i1, i2, i3) { const float4 v = vb[r]; \
  const h2 x0 = B2(v.x), x1 = B2(v.y), x2 = B2(v.z), x3 = B2(v.w); \
  FD(pa##i0, x0, zA0); FD(pb##i0, x0, zB0); FD(pc##i0, x0, zC0); FD(pd##i0, x0, zD0); \
  FD(pa##i1, x1, zA1); FD(pb##i1, x1, zB1); FD(pc##i1, x1, zC1); FD(pd##i1, x1, zD1); \
  FD(pa##i2, x2, zA0); FD(pb##i2, x2, zB0); FD(pc##i2, x2, zC0); FD(pd##i2, x2, zD0); \
  FD(pa##i3, x3, zA1); FD(pb##i3, x3, zB1); FD(pc##i3, x3, zC1); FD(pd##i3, x3, zD1); }

// ---------------- consumer weight machinery (100 h2 / thread) --------------
#define CDW(i) h2 ca##i, cb##i;
// packed float4 j = (ca_{2j}, cb_{2j}, ca_{2j+1}, cb_{2j+1})
#define LWCK2(j, i0, i1) { const float4 v = gwc[j]; \
  ca##i0 = B2(v.x); cb##i0 = B2(v.y); ca##i1 = B2(v.z); cb##i1 = B2(v.w); }

#define DOTC(r, i0, i1, i2, i3) { const float4 v = vb[r]; \
  const h2 x0 = B2(v.x), x1 = B2(v.y), x2 = B2(v.z), x3 = B2(v.w); \
  FD(ca##i0, x0, zA0); FD(cb##i0, x0, zB0); \
  FD(ca##i1, x1, zA1); FD(cb##i1, x1, zB1); \
  FD(ca##i2, x2, zA0); FD(cb##i2, x2, zB0); \
  FD(ca##i3, x3, zA1); FD(cb##i3, x3, zB1); }

#define DOTCT { const float2 v = *tb; \
  const h2 x0 = B2(v.x), x1 = B2(v.y); \
  FD(ca48, x0, zA0); FD(cb48, x0, zB0); \
  FD(ca49, x1, zA1); FD(cb49, x1, zB1); }

// ---------------- cross-lane primitives (DPP, pure VALU) --------------------
// 0xB1 = quad_perm [1,0,3,2] (xor 1), 0x4E = quad_perm [2,3,0,1] (xor 2)
static __device__ __forceinline__ float qsum4(float z) {
    int p1 = __builtin_amdgcn_update_dpp(0, __builtin_bit_cast(int, z),
                                         0xB1, 0xF, 0xF, true);
    float s1 = z + __builtin_bit_cast(float, p1);
    int p2 = __builtin_amdgcn_update_dpp(0, __builtin_bit_cast(int, s1),
                                         0x4E, 0xF, 0xF, true);
    return s1 + __builtin_bit_cast(float, p2);
}
static __device__ __forceinline__ float psum2(float z) {
    int p1 = __builtin_amdgcn_update_dpp(0, __builtin_bit_cast(int, z),
                                         0xB1, 0xF, 0xF, true);
    return z + __builtin_bit_cast(float, p1);
}
static __device__ __forceinline__ float xswap2(float z) {   // value from lane^2
    int p2 = __builtin_amdgcn_update_dpp(0, __builtin_bit_cast(int, z),
                                         0x4E, 0xF, 0xF, true);
    return __builtin_bit_cast(float, p2);
}
static __device__ __forceinline__ float sig(float z) {
    return 1.0f / (1.0f + __expf(-z));
}

// ---------------- prep kernel: pack weights to f16 in per-thread order -----
// producer combined column: K = [conv-x(64) ; U1(100) ; pad(28)] -> 192
static __device__ __forceinline__ _Float16 pwv(const float* __restrict__ W,
                                               const float* __restrict__ U,
                                               int c, int k) {
    float v = (k < FF) ? W[k * G4 + c] : (k < FF + HH ? U[(k - FF) * G4 + c] : 0.0f);
    return (_Float16)v;
}
// consumer combined column: K = [W2(100) ; U2(100)] -> 200 (no pad weights)
static __device__ __forceinline__ _Float16 cwv(const float* __restrict__ W,
                                               const float* __restrict__ U,
                                               int c, int k) {
    return (_Float16)((k < HH) ? W[k * G4 + c] : U[(k - HH) * G4 + c]);
}

__global__ void prep_weights(const float* __restrict__ w1, const float* __restrict__ u1,
                             const float* __restrict__ w2, const float* __restrict__ u2,
                             h2* __restrict__ ws)
{
    const int idx = blockIdx.x * 256 + threadIdx.x;   // h2 index
    if (idx >= NPH2 + NCH2) return;
    _Float16 lo, hi;
    if (idx < NPH2) {
        // producer thread rt: 24 quads (pair q, gates 0..3)
        const int rt = idx / 96, r = idx % 96;
        const int q = r >> 2, g = r & 3;
        const int p = rt >> 2, sq = rt & 3;
        const int c = g * HH + p;
        const int k = sq * 48 + 2 * q;
        lo = pwv(w1, u1, c, k); hi = pwv(w1, u1, c, k + 1);
    } else {
        // consumer thread rt: 25 float4 = (ca_{2j},cb_{2j},ca_{2j+1},cb_{2j+1})
        const int j2 = idx - NPH2;
        const int rt = j2 / 100, r = j2 % 100;
        const int jj = r >> 2;
        const int ii = 2 * jj + ((r & 3) >> 1);       // pair index 0..49
        const int gg = r & 1;                         // gate within pair
        const int p = rt >> 2, g2 = (rt >> 1) & 1, kh = rt & 1;
        const int c = (2 * g2 + gg) * HH + p;
        const int k = kh * HH + 2 * ii;               // 0..199, no pads
        lo = cwv(w2, u2, c, k); hi = cwv(w2, u2, c, k + 1);
    }
    ws[idx] = h2{lo, hi};
}

// ---------------- main kernel ----------------------------------------------
__global__ __launch_bounds__(1024, 4)
void fused_lstm_kernel(const float* __restrict__ s,       // [B,T]
                       const float* __restrict__ conv_w,  // [2,1,F]
                       const float* __restrict__ conv_b,  // [F]
                       const float* __restrict__ b1,
                       const float* __restrict__ b2,
                       const float* __restrict__ dw, const float* __restrict__ db,
                       const h2* __restrict__ wpk,        // packed weights
                       float* __restrict__ out)           // [B,3]
{
    const int tid = threadIdx.x;
    const int b   = blockIdx.x;

    __shared__ float s_buf[TT];                        // 8 KB input row
    __shared__ __align__(16) _Float16 X1[2 * K1];      // producer operand ring
    __shared__ __align__(16) _Float16 X2[2 * K2];      // consumer operand ring

    for (int i = tid; i < TT; i += 1024) s_buf[i] = s[(size_t)b * TT + i];
    if (tid < 2 * K1) X1[tid] = (_Float16)0.0f;        // pads stay 0 forever
    if (tid < 2 * K2) X2[tid] = (_Float16)0.0f;
    __syncthreads();                                   // (A)

    if (tid < 448) {
        // ============ PRODUCER: waves 0-6, 400 dot threads ============
        const int rt     = tid;
        const int active = (rt < 400);
        const int lrt    = active ? rt : 0;
        const int p      = lrt >> 2;                   // unit
        const int sq     = lrt & 3;                    // K-quarter
        const int cA = p, cB = HH + p, cC = 2 * HH + p, cD = 3 * HH + p;
        const int kb = sq * 48;                        // quarter base (halves)

        const float4* gwp = (const float4*)(wpk + (size_t)lrt * 96);
        L24(PDW)
        L24(LWPK)
        const float bA = b1[cA], bB = b1[cB], bC = b1[cC], bD = b1[cD];
        __syncthreads();                               // (B)

        float c = 0.0f;
        for (int t = 0; t <= TP; ++t) {
            if (t < TP && active) {
                _Float16* cur = X1 + (t & 1) * K1;
                _Float16* nx1 = X1 + ((t & 1) ^ 1) * K1;
                _Float16* x2n = X2 + ((t & 1) ^ 1) * K2;
                float zA0 = 0.f, zA1 = 0.f, zB0 = 0.f, zB1 = 0.f;
                float zC0 = 0.f, zC1 = 0.f, zD0 = 0.f, zD1 = 0.f;
                const float4* vb = (const float4*)(cur + kb);
                DOTP(0, 0, 1, 2, 3)     DOTP(1, 4, 5, 6, 7)
                DOTP(2, 8, 9, 10, 11)   DOTP(3, 12, 13, 14, 15)
                DOTP(4, 16, 17, 18, 19) DOTP(5, 20, 21, 22, 23)
                const float zi = qsum4(zA0 + zA1) + bA;
                const float zf = qsum4(zB0 + zB1) + bB;
                const float zg = qsum4(zC0 + zC1) + bC;
                const float zo = qsum4(zD0 + zD1) + bD;
                c = fmaf(sig(zf), c, sig(zi) * fmaxf(zg, 0.f));
                const float h = sig(zo) * fmaxf(c, 0.f);
                if (sq == 0) {
                    const _Float16 hq = (_Float16)h;
                    nx1[FF + p] = hq;                  // h1 for LSTM1(t+1)
                    x2n[p]      = hq;                  // x2 for LSTM2
                }
            }
            __syncthreads();                           // (C)
        }
    } else if (tid < 896) {
        // ============ CONSUMER: waves 7-13, 400 dot threads ============
        const int rt     = tid - 448;
        const int active = (rt < 400);
        const int lrt    = active ? rt : 0;
        const int p      = lrt >> 2;                   // unit
        const int g2     = (lrt >> 1) & 1;             // gate pair: 0->{i,f}, 1->{g,o}
        const int kh     = lrt & 1;                    // K-half
        const int cL = (2 * g2) * HH + p;              // first gate col
        const int cH = cL + HH;                        // second gate col
        const int kb = kh * 104;                       // operand half base (halves)

        const float4* gwc = (const float4*)(wpk + NPH2 + (size_t)lrt * 100);
        L50(CDW)
        LWCK2(0,0,1)    LWCK2(1,2,3)    LWCK2(2,4,5)    LWCK2(3,6,7)
        LWCK2(4,8,9)    LWCK2(5,10,11)  LWCK2(6,12,13)  LWCK2(7,14,15)
        LWCK2(8,16,17)  LWCK2(9,18,19)  LWCK2(10,20,21) LWCK2(11,22,23)
        LWCK2(12,24,25) LWCK2(13,26,27) LWCK2(14,28,29) LWCK2(15,30,31)
        LWCK2(16,32,33) LWCK2(17,34,35) LWCK2(18,36,37) LWCK2(19,38,39)
        LWCK2(20,40,41) LWCK2(21,42,43) LWCK2(22,44,45) LWCK2(23,46,47)
        LWCK2(24,48,49)
        const float bL = b2[cL], bH = b2[cH];
        __syncthreads();                               // (B)

        float c = 0.0f;
        for (int t = 0; t <= TP; ++t) {
            if (t >= 1 && active) {                    // consumer step t-1
                _Float16* cur = X2 + (t & 1) * K2;
                float zA0 = 0.f, zA1 = 0.f, zB0 = 0.f, zB1 = 0.f;
                const float4* vb = (const float4*)(cur + kb);
                DOTC(0, 0, 1, 2, 3)      DOTC(1, 4, 5, 6, 7)
                DOTC(2, 8, 9, 10, 11)    DOTC(3, 12, 13, 14, 15)
                DOTC(4, 16, 17, 18, 19)  DOTC(5, 20, 21, 22, 23)
                DOTC(6, 24, 25, 26, 27)  DOTC(7, 28, 29, 30, 31)
                DOTC(8, 32, 33, 34, 35)  DOTC(9, 36, 37, 38, 39)
                DOTC(10, 40, 41, 42, 43) DOTC(11, 44, 45, 46, 47)
                const float2* tb = (const float2*)(cur + kb + 96);
                DOTCT
                // sum K-halves (partner = lane^1, same p,g2)
                const float za = psum2(zA0 + zA1) + bL;
                const float zb = psum2(zB0 + zB1) + bH;
                // exchange gate pairs (partner = lane^2, same p,kh)
                const float oa = xswap2(za);
                const float ob = xswap2(zb);
                const float zi = g2 ? oa : za;
                const float zf = g2 ? ob : zb;
                const float zg = g2 ? za : oa;
                const float zo = g2 ? zb : ob;
                c = fmaf(sig(zf), c, sig(zi) * fmaxf(zg, 0.f));
                const float h = sig(zo) * fmaxf(c, 0.f);
                if ((rt & 3) == 0)
                    X2[((t & 1) ^ 1) * K2 + 104 + p] = (_Float16)h;
            }
            __syncthreads();                           // (C)
        }

        // final h2(TP-1) was written at iter TP into slot ((TP&1)^1)=0
        if (rt == 0) {
            float l[3];
#pragma unroll
            for (int a = 0; a < 3; ++a) {
                float acc = db[a];
                for (int j = 0; j < HH; ++j)
                    acc = fmaf((float)X2[104 + j], dw[j * 3 + a], acc);
                l[a] = acc;
            }
            const float m = fmaxf(l[0], fmaxf(l[1], l[2]));
            const float e0 = __expf(l[0] - m), e1 = __expf(l[1] - m), e2 = __expf(l[2] - m);
            const float inv = 1.0f / (e0 + e1 + e2);
            out[b * 3 + 0] = e0 * inv;
            out[b * 3 + 1] = e1 * inv;
            out[b * 3 + 2] = e2 * inv;
        }
    } else if (tid < 960) {
        // ============ CONV: wave 14, 64 threads (1 filter each) ============
        const int f = tid - 896;
        const float kv0 = conv_w[f], kv1 = conv_w[FF + f], kc0 = conv_b[f];
        // x(0) into slot 0
        X1[f] = (_Float16)fmaxf(fmaf(s_buf[0], kv0, fmaf(s_buf[1], kv1, kc0)), 0.f);
        __syncthreads();                               // (B)

        for (int t = 0; t <= TP; ++t) {
            if (t + 1 < TP) {                          // conv x(t+1) into next slot
                _Float16* nx1 = X1 + ((t & 1) ^ 1) * K1;
                nx1[f] = (_Float16)fmaxf(fmaf(s_buf[t + 1], kv0, fmaf(s_buf[t + 2], kv1, kc0)), 0.f);
            }
            __syncthreads();                           // (C)
        }
    } else {
        // ============ wave 15: barrier companion only ============
        __syncthreads();                               // (B)
        for (int t = 0; t <= TP; ++t)
            __syncthreads();                           // (C)
    }
}

// ---------------- launch ----------------------------------------------------
extern "C" void kernel_launch(void* const* d_in, const int* in_sizes, int n_in,
                              void* d_out, int out_size, void* d_ws, size_t ws_size,
                              hipStream_t stream) {
    const float* s      = (const float*)d_in[0];
    const float* conv_w = (const float*)d_in[1];
    const float* conv_b = (const float*)d_in[2];
    const float* w1     = (const float*)d_in[3];
    const float* u1     = (const float*)d_in[4];
    const float* b1     = (const float*)d_in[5];
    const float* w2     = (const float*)d_in[6];
    const float* u2     = (const float*)d_in[7];
    const float* b2     = (const float*)d_in[8];
    const float* dw     = (const float*)d_in[9];
    const float* db     = (const float*)d_in[10];

    h2* ws = (h2*)d_ws;
    const int nh2 = NPH2 + NCH2;
    prep_weights<<<(nh2 + 255) / 256, 256, 0, stream>>>(w1, u1, w2, u2, ws);
    fused_lstm_kernel<<<BB, 1024, 0, stream>>>(
        s, conv_w, conv_b, b1, b2, dw, db, ws, (float*)d_out);
}

// Round 8
// 2328.339 us; speedup vs baseline: 1.2344x; 1.2344x over previous
//
#include <hip/hip_runtime.h>
#include <math.h>

// Conv1D(k=2,F=64,relu) -> LSTM1(H=100, relu cell, seq) -> LSTM2 (last) ->
// Dense(3) -> softmax.  B=128, T=2048, T'=2047.
//
// Round-13 = r11 (2328us best: 512thr, 2 waves/SIMD, packed f16 weights,
// DPP pair reduction) + post-barrier-head removal via x-register-prefetch:
//  * conv runs TWO steps ahead into xr[3][64] (depth-3 LDS ring).
//  * producer K re-split: each K-half = [x 32 halves | h 56 halves]:
//      even: x[0,32)  + h[0,56)        odd: x[32,64) + h[56,100)+pad12
//    weights re-packed to match (prep kernel).
//  * producer issues the 4 ds_read_b128 for x(t+1) in the TAIL of step t
//    (xr slot written at t-1, barrier-separated -> safe) and holds them in
//    registers across the barrier: each step opens with 64 fdot2 issued
//    straight from regs while the 7 h-part ds_reads fly.  This fills the
//    ~120-250cy post-barrier LDS-latency head where both phase-locked
//    waves/SIMD previously stalled together.
//  * h operand ring hr[2][112] ([h100|pad12] per slot); consumer r11-verbatim
//    (X2[2][208], psum2 pair reduction, odd lane writes h2).
//  r12 post-mortem: 4 waves/SIMD (128 reg/wave) forces ~40 weights into
//  AGPRs -> accvgpr shuttle per use -> +23% despite 2x TLP and zero spill.
//  2 waves/SIMD (256 reg/wave) is the only shape fitting 176-200 h2 weights.

typedef _Float16 h2 __attribute__((ext_vector_type(2)));

#define BB 128
#define TT 2048
#define TP 2047
#define HH 100
#define G4 400
#define FF 64

#define K2 208   // consumer operand halves: [x2(100); pad4 ; h2(100); pad4]

#define NPH2 (200 * 176)   // producer packed h2 (200 thr x 44 quads x 4 gates)
#define NCH2 (200 * 200)   // consumer packed h2 (200 thr x 50 quads x 4 gates)

#define L44(X) X(0) X(1) X(2) X(3) X(4) X(5) X(6) X(7) X(8) X(9) \
 X(10) X(11) X(12) X(13) X(14) X(15) X(16) X(17) X(18) X(19) \
 X(20) X(21) X(22) X(23) X(24) X(25) X(26) X(27) X(28) X(29) \
 X(30) X(31) X(32) X(33) X(34) X(35) X(36) X(37) X(38) X(39) \
 X(40) X(41) X(42) X(43)
#define L50(X) L44(X) X(44) X(45) X(46) X(47) X(48) X(49)

#define DW(q) h2 wa##q, wb##q, wc##q, wd##q;

// packed-weight loads: quad q = (pair q, gates 0..3), 16B contiguous
#define LWPK(q) { const float4 v = gwp[q]; \
  wa##q = B2(v.x); wb##q = B2(v.y); wc##q = B2(v.z); wd##q = B2(v.w); }
#define LWCK(q) { const float4 v = gwc[q]; \
  wa##q = B2(v.x); wb##q = B2(v.y); wc##q = B2(v.z); wd##q = B2(v.w); }

#define FD(w, x, acc) acc = __builtin_amdgcn_fdot2(w, x, acc, false)
#define B2(f) __builtin_bit_cast(h2, f)

// dot from an LDS-loaded float4 (operand read vb[r])
#define DOT4(r, q0, q1, q2, q3) { const float4 v = vb[r]; \
  const h2 x0 = B2(v.x), x1 = B2(v.y), x2 = B2(v.z), x3 = B2(v.w); \
  FD(wa##q0, x0, zA0); FD(wb##q0, x0, zB0); FD(wc##q0, x0, zC0); FD(wd##q0, x0, zD0); \
  FD(wa##q1, x1, zA1); FD(wb##q1, x1, zB1); FD(wc##q1, x1, zC1); FD(wd##q1, x1, zD1); \
  FD(wa##q2, x2, zA0); FD(wb##q2, x2, zB0); FD(wc##q2, x2, zC0); FD(wd##q2, x2, zD0); \
  FD(wa##q3, x3, zA1); FD(wb##q3, x3, zB1); FD(wc##q3, x3, zC1); FD(wd##q3, x3, zD1); }

// dot from a float4 already held in registers (x-prefetch)
#define DOTX(vv, q0, q1, q2, q3) { \
  const h2 x0 = B2(vv.x), x1 = B2(vv.y), x2 = B2(vv.z), x3 = B2(vv.w); \
  FD(wa##q0, x0, zA0); FD(wb##q0, x0, zB0); FD(wc##q0, x0, zC0); FD(wd##q0, x0, zD0); \
  FD(wa##q1, x1, zA1); FD(wb##q1, x1, zB1); FD(wc##q1, x1, zC1); FD(wd##q1, x1, zD1); \
  FD(wa##q2, x2, zA0); FD(wb##q2, x2, zB0); FD(wc##q2, x2, zC0); FD(wd##q2, x2, zD0); \
  FD(wa##q3, x3, zA1); FD(wb##q3, x3, zB1); FD(wc##q3, x3, zC1); FD(wd##q3, x3, zD1); }

#define DOTT(q0, q1) { const float2 v = *tb; \
  const h2 x0 = B2(v.x), x1 = B2(v.y); \
  FD(wa##q0, x0, zA0); FD(wb##q0, x0, zB0); FD(wc##q0, x0, zC0); FD(wd##q0, x0, zD0); \
  FD(wa##q1, x1, zA1); FD(wb##q1, x1, zB1); FD(wc##q1, x1, zC1); FD(wd##q1, x1, zD1); }

// lane-pair sum via DPP quad_perm xor-1 (pure VALU; pairs never straddle a quad)
static __device__ __forceinline__ float psum2(float z) {
    int p1 = __builtin_amdgcn_update_dpp(0, __builtin_bit_cast(int, z),
                                         0xB1, 0xF, 0xF, true);
    return z + __builtin_bit_cast(float, p1);
}
static __device__ __forceinline__ float sig(float z) {
    return 1.0f / (1.0f + __expf(-z));
}

// ---------------- prep kernel: pack weights to f16 in per-thread order -----
// producer combined column: K = [conv-x(64) ; U1(100) ; pad(12)] -> 176
static __device__ __forceinline__ _Float16 pwv(const float* __restrict__ W,
                                               const float* __restrict__ U,
                                               int c, int k) {
    float v = (k < FF) ? W[k * G4 + c] : (k < FF + HH ? U[(k - FF) * G4 + c] : 0.0f);
    return (_Float16)v;
}
// consumer combined column: K = [W2(100) ; U2(100)] -> 200 (no pad weights)
static __device__ __forceinline__ _Float16 cwv(const float* __restrict__ W,
                                               const float* __restrict__ U,
                                               int c, int k) {
    return (_Float16)((k < HH) ? W[k * G4 + c] : U[(k - HH) * G4 + c]);
}

__global__ void prep_weights(const float* __restrict__ w1, const float* __restrict__ u1,
                             const float* __restrict__ w2, const float* __restrict__ u2,
                             h2* __restrict__ ws)
{
    const int idx = blockIdx.x * 256 + threadIdx.x;   // h2 index
    if (idx >= NPH2 + NCH2) return;
    _Float16 lo, hi;
    if (idx < NPH2) {
        // producer thread rt: 44 quads; new K-split:
        //  even: q<16 -> x[2q] ; q>=16 -> h[2(q-16)]      (x[0,32) + h[0,56))
        //  odd : q<16 -> x[32+2q] ; q>=16 -> h[56+2(q-16)] (+pad -> 0)
        const int rt = idx / 176, r = idx % 176;
        const int q = r >> 2, g = r & 3;              // quad, gate
        const int p = rt >> 1, odd = rt & 1;
        const int c = g * HH + p;
        int k;
        if (!odd) k = (q < 16) ? 2 * q : FF + 2 * (q - 16);
        else      k = (q < 16) ? 32 + 2 * q : FF + 56 + 2 * (q - 16); // >=164 -> 0
        lo = pwv(w1, u1, c, k); hi = pwv(w1, u1, c, k + 1);
    } else {
        // consumer thread rt: 50 quads over K-half kw (r11 layout, unchanged)
        const int j = idx - NPH2;
        const int rt = j / 200, r = j % 200;
        const int i = r >> 2, g = r & 3;
        const int p = rt >> 1, kw = (rt & 1) * 100;
        const int c = g * HH + p;
        const int k = kw + 2 * i;
        lo = cwv(w2, u2, c, k); hi = cwv(w2, u2, c, k + 1);
    }
    ws[idx] = h2{lo, hi};
}

// ---------------- main kernel ----------------------------------------------
__global__ __launch_bounds__(512, 2)
void fused_lstm_kernel(const float* __restrict__ s,       // [B,T]
                       const float* __restrict__ conv_w,  // [2,1,F]
                       const float* __restrict__ conv_b,  // [F]
                       const float* __restrict__ b1,
                       const float* __restrict__ b2,
                       const float* __restrict__ dw, const float* __restrict__ db,
                       const h2* __restrict__ wpk,        // packed weights
                       float* __restrict__ out)           // [B,3]
{
    const int tid = threadIdx.x;
    const int b   = blockIdx.x;

    __shared__ float s_buf[TT];                        // 8 KB input row
    __shared__ __align__(16) _Float16 xr[3 * 64];      // conv-x ring, 2 ahead
    __shared__ __align__(16) _Float16 hr[2 * 112];     // h1 ring [h(100)|pad12]
    __shared__ __align__(16) _Float16 X2[2 * K2];      // consumer operand ring

    for (int i = tid; i < TT; i += 512) s_buf[i] = s[(size_t)b * TT + i];
    if (tid < 2 * 112) hr[tid] = (_Float16)0.0f;       // pads stay 0 forever
    if (tid < 2 * K2)  X2[tid] = (_Float16)0.0f;
    __syncthreads();                                   // (A)

    if (tid < 256) {
        // ================= PRODUCER waves: conv + LSTM1 =================
        const int rt  = tid;
        const int p   = (rt < 200) ? (rt >> 1) : 0;
        const int odd = rt & 1;
        const int cA = p, cB = HH + p, cC = 2 * HH + p, cD = 3 * HH + p;

        const float4* gwp = (const float4*)(wpk + (size_t)rt * 44 * 4);
        L44(DW)
        L44(LWPK)
        const float biA = b1[cA], biB = b1[cB], biC = b1[cC], biD = b1[cD];

        float cv0 = 0.f, cv1 = 0.f, cb0 = 0.f, cv0b = 0.f, cv1b = 0.f, cb0b = 0.f;
        const int f1 = rt - 200;
        if (rt >= 200) {
            cv0 = conv_w[f1]; cv1 = conv_w[FF + f1]; cb0 = conv_b[f1];
            if (f1 < 8) { cv0b = conv_w[56 + f1]; cv1b = conv_w[FF + 56 + f1]; cb0b = conv_b[56 + f1]; }
        }
        if (rt >= 200) {                               // x(0) -> xr[0], x(1) -> xr[1]
            xr[f1] = (_Float16)fmaxf(fmaf(s_buf[0], cv0, fmaf(s_buf[1], cv1, cb0)), 0.f);
            xr[64 + f1] = (_Float16)fmaxf(fmaf(s_buf[1], cv0, fmaf(s_buf[2], cv1, cb0)), 0.f);
            if (f1 < 8) {
                xr[56 + f1] = (_Float16)fmaxf(fmaf(s_buf[0], cv0b, fmaf(s_buf[1], cv1b, cb0b)), 0.f);
                xr[64 + 56 + f1] = (_Float16)fmaxf(fmaf(s_buf[1], cv0b, fmaf(s_buf[2], cv1b, cb0b)), 0.f);
            }
        }
        __syncthreads();                               // (B)

        float4 tx0, tx1, tx2, tx3;                     // x(t) held across barrier
        if (rt < 200) {                                // prefetch x(0)
            const float4* xb = (const float4*)(xr + odd * 32);
            tx0 = xb[0]; tx1 = xb[1]; tx2 = xb[2]; tx3 = xb[3];
        }
        int xs = 0;                                    // slot currently in tx
        int cs = 2;                                    // conv write slot (t+2)

        float c = 0.0f;
        for (int t = 0; t <= TP; ++t) {
            if (t < TP) {
                if (rt < 200) {
                    float zA0 = 0.f, zA1 = 0.f, zB0 = 0.f, zB1 = 0.f;
                    float zC0 = 0.f, zC1 = 0.f, zD0 = 0.f, zD1 = 0.f;
                    // x-part straight from registers (issued last step)
                    DOTX(tx0, 0, 1, 2, 3)   DOTX(tx1, 4, 5, 6, 7)
                    DOTX(tx2, 8, 9, 10, 11) DOTX(tx3, 12, 13, 14, 15)
                    // h-part from hr ring (7 ds_read_b128)
                    const float4* vb = (const float4*)(hr + (t & 1) * 112 + (odd ? 56 : 0));
                    DOT4(0, 16, 17, 18, 19) DOT4(1, 20, 21, 22, 23)
                    DOT4(2, 24, 25, 26, 27) DOT4(3, 28, 29, 30, 31)
                    DOT4(4, 32, 33, 34, 35) DOT4(5, 36, 37, 38, 39)
                    DOT4(6, 40, 41, 42, 43)
                    const float zi = psum2(zA0 + zA1) + biA;
                    const float zf = psum2(zB0 + zB1) + biB;
                    const float zg = psum2(zC0 + zC1) + biC;
                    const float zo = psum2(zD0 + zD1) + biD;
                    const float gi = sig(zi), gf = sig(zf), go = sig(zo);
                    const float gg = fmaxf(zg, 0.f);
                    c = fmaf(gf, c, gi * gg);
                    const float h = go * fmaxf(c, 0.f);
                    if (odd) {
                        const _Float16 hq = (_Float16)h;
                        hr[((t & 1) ^ 1) * 112 + p] = hq;          // h1 for LSTM1(t+1)
                        X2[((t & 1) ^ 1) * K2 + p]  = hq;          // x2 for LSTM2
                    }
                    if (t + 1 < TP) {                  // issue x(t+1) reads (tail)
                        xs = (xs == 2) ? 0 : xs + 1;
                        const float4* xb = (const float4*)(xr + xs * 64 + odd * 32);
                        tx0 = xb[0]; tx1 = xb[1]; tx2 = xb[2]; tx3 = xb[3];
                    }
                } else if (t + 2 < TP) {               // conv x(t+2), 2 ahead
                    _Float16* xw = xr + cs * 64;
                    xw[f1] = (_Float16)fmaxf(fmaf(s_buf[t + 2], cv0, fmaf(s_buf[t + 3], cv1, cb0)), 0.f);
                    if (f1 < 8)
                        xw[56 + f1] = (_Float16)fmaxf(fmaf(s_buf[t + 2], cv0b, fmaf(s_buf[t + 3], cv1b, cb0b)), 0.f);
                    cs = (cs == 2) ? 0 : cs + 1;
                }
            }
            __syncthreads();                           // (C) one per step
        }
    } else {
        // ================= CONSUMER waves: LSTM2 + dense + softmax ==========
        const int rt  = tid - 256;
        const int p   = (rt < 200) ? (rt >> 1) : 0;
        const int odd = rt & 1;
        const int cA = p, cB = HH + p, cC = 2 * HH + p, cD = 3 * HH + p;
        const int kb = odd ? 104 : 0;                  // operand K-half base

        const float4* gwc = (const float4*)(wpk + NPH2 + (size_t)rt * 50 * 4);
        L50(DW)
        L50(LWCK)
        const float biA = b2[cA], biB = b2[cB], biC = b2[cC], biD = b2[cD];
        __syncthreads();                               // (B)

        float c = 0.0f;
        for (int t = 0; t <= TP; ++t) {
            if (t >= 1 && rt < 200) {                  // consumer step t-1
                _Float16* cur = X2 + (t & 1) * K2;
                float zA0 = 0.f, zA1 = 0.f, zB0 = 0.f, zB1 = 0.f;
                float zC0 = 0.f, zC1 = 0.f, zD0 = 0.f, zD1 = 0.f;
                const float4* vb = (const float4*)(cur + kb);
                DOT4(0,0,1,2,3)     DOT4(1,4,5,6,7)     DOT4(2,8,9,10,11)
                DOT4(3,12,13,14,15) DOT4(4,16,17,18,19) DOT4(5,20,21,22,23)
                DOT4(6,24,25,26,27) DOT4(7,28,29,30,31) DOT4(8,32,33,34,35)
                DOT4(9,36,37,38,39) DOT4(10,40,41,42,43) DOT4(11,44,45,46,47)
                const float2* tb = (const float2*)(cur + kb + 96);
                DOTT(48, 49)
                const float zi = psum2(zA0 + zA1) + biA;
                const float zf = psum2(zB0 + zB1) + biB;
                const float zg = psum2(zC0 + zC1) + biC;
                const float zo = psum2(zD0 + zD1) + biD;
                const float gi = sig(zi), gf = sig(zf), go = sig(zo);
                const float gg = fmaxf(zg, 0.f);
                c = fmaf(gf, c, gi * gg);
                const float h = go * fmaxf(c, 0.f);
                if (odd) X2[((t & 1) ^ 1) * K2 + 104 + p] = (_Float16)h;
            }
            __syncthreads();                           // (C) one per step
        }

        // final h2(TP-1) was written at iter TP into slot ((TP&1)^1)=0
        if (rt == 0) {
            float l[3];
#pragma unroll
            for (int a = 0; a < 3; ++a) {
                float acc = db[a];
                for (int j = 0; j < HH; ++j)
                    acc = fmaf((float)X2[104 + j], dw[j * 3 + a], acc);
                l[a] = acc;
            }
            const float m = fmaxf(l[0], fmaxf(l[1], l[2]));
            const float e0 = __expf(l[0] - m), e1 = __expf(l[1] - m), e2 = __expf(l[2] - m);
            const float inv = 1.0f / (e0 + e1 + e2);
            out[b * 3 + 0] = e0 * inv;
            out[b * 3 + 1] = e1 * inv;
            out[b * 3 + 2] = e2 * inv;
        }
    }
}

// ---------------- launch ----------------------------------------------------
extern "C" void kernel_launch(void* const* d_in, const int* in_sizes, int n_in,
                              void* d_out, int out_size, void* d_ws, size_t ws_size,
                              hipStream_t stream) {
    const float* s      = (const float*)d_in[0];
    const float* conv_w = (const float*)d_in[1];
    const float* conv_b = (const float*)d_in[2];
    const float* w1     = (const float*)d_in[3];
    const float* u1     = (const float*)d_in[4];
    const float* b1     = (const float*)d_in[5];
    const float* w2     = (const float*)d_in[6];
    const float* u2     = (const float*)d_in[7];
    const float* b2     = (const float*)d_in[8];
    const float* dw     = (const float*)d_in[9];
    const float* db     = (const float*)d_in[10];

    h2* ws = (h2*)d_ws;
    const int nh2 = NPH2 + NCH2;
    prep_weights<<<(nh2 + 255) / 256, 256, 0, stream>>>(w1, u1, w2, u2, ws);
    fused_lstm_kernel<<<BB, 512, 0, stream>>>(
        s, conv_w, conv_b, b1, b2, dw, db, ws, (float*)d_out);
}

// Round 9
// 1878.822 us; speedup vs baseline: 1.5297x; 1.2393x over previous
//
#include <hip/hip_runtime.h>
#include <math.h>

// Conv1D(k=2,F=64,relu) -> LSTM1(H=100, relu cell, seq) -> LSTM2 (last) ->
// Dense(3) -> softmax.  B=128, T=2048, T'=2047.
//
// Round-14: LAYER-SPLIT PIPELINE across 256 blocks (2 per batch element).
//  r5/r11/r13 all sit at 2330-2480us: the one-CU producer+consumer structure
//  has a fixed ~2700cy/step serialization floor and idles half the GPU.
//  LSTM1->LSTM2 is feed-forward, so: block b (<128) = conv+LSTM1 producer;
//  block b+128 = LSTM2 consumer, lagging one 64-step chunk.
//   * h1 transport: producer packs 2 f16 per dword (ds_swizzle xor-4) and
//     stores 50 dwords/step with device-scope atomic stores (sc1 -> LLC,
//     no wbl2 flush).  Per chunk: storers s_waitcnt vmcnt(0), barrier, then
//     tid0 RELEASE-adds the chunk flag.  4-slot ring + consumer ack flag.
//   * consumer polls flag (ACQUIRE, bounded spin), stages the chunk into
//     LDS with device-scope loads (stale-proof across graph replays; flags
//     re-zeroed by hipMemsetAsync each launch), acks, then runs 64 steps.
//   * both roles use the r12-PROVEN (unit p, K-quarter sq) 4-way split with
//     qsum4 DPP reduction, 400 dot threads, 2 waves/SIMD -> 256 regs/wave:
//     producer 96 h2 weights/thread (K1=192: x64|h100|pad28, quarter 48),
//     consumer 112 h2 (K2'=224: W2 100|pad12|U2 100|pad12, quarter 56 ->
//     7 aligned float4 reads, no tail).  All weights arch-resident (the
//     AGPR pressure that killed r12 is gone).
//   * weights prepacked f16 by prep kernel (r11-proven spill fix).
//  VGPR>128 forces 1 block/CU -> all 256 blocks co-resident (no deadlock);
//  spins are iteration-bounded anyway.

typedef _Float16 h2 __attribute__((ext_vector_type(2)));

#define TT 2048
#define TP 2047
#define HH 100
#define G4 400
#define FF 64
#define NB 128

#define K1 192               // producer operand halves [x64|h100|pad28]
#define QC 112               // consumer row halves [100|pad12]; quarter 56
#define NPH2 (400 * 96)      // producer packed h2
#define NCH2 (400 * 112)     // consumer packed h2
#define CHK 64
#define NCHUNK 32            // ceil(2047/64)
#define RINGC 4
#define CHUNK_DW (CHK * 50)  // 3200 dwords per chunk slot

// ws layout in h2 (4B) units
#define WS_FLAGS (NPH2 + NCH2)     // pflag[128], aflag[128]
#define WS_RING  (WS_FLAGS + 256)  // 128 * RINGC * CHUNK_DW dwords

#define L24(X) X(0) X(1) X(2) X(3) X(4) X(5) X(6) X(7) X(8) X(9) \
 X(10) X(11) X(12) X(13) X(14) X(15) X(16) X(17) X(18) X(19) \
 X(20) X(21) X(22) X(23)
#define L28(X) L24(X) X(24) X(25) X(26) X(27)

#define FD(w, x, acc) acc = __builtin_amdgcn_fdot2(w, x, acc, false)
#define B2(f) __builtin_bit_cast(h2, f)

#define DW4(i) h2 wa##i, wb##i, wc##i, wd##i;
#define LPK(i) { const float4 v = gptr[i]; \
  wa##i = B2(v.x); wb##i = B2(v.y); wc##i = B2(v.z); wd##i = B2(v.w); }

// one float4 operand chunk feeds 4 gates (8 chains via element parity)
#define DOTP(r, i0, i1, i2, i3) { const float4 v = vb[r]; \
  const h2 x0 = B2(v.x), x1 = B2(v.y), x2 = B2(v.z), x3 = B2(v.w); \
  FD(wa##i0, x0, zA0); FD(wb##i0, x0, zB0); FD(wc##i0, x0, zC0); FD(wd##i0, x0, zD0); \
  FD(wa##i1, x1, zA1); FD(wb##i1, x1, zB1); FD(wc##i1, x1, zC1); FD(wd##i1, x1, zD1); \
  FD(wa##i2, x2, zA0); FD(wb##i2, x2, zB0); FD(wc##i2, x2, zC0); FD(wd##i2, x2, zD0); \
  FD(wa##i3, x3, zA1); FD(wb##i3, x3, zB1); FD(wc##i3, x3, zC1); FD(wd##i3, x3, zD1); }

// 0xB1 = quad_perm xor-1, 0x4E = quad_perm xor-2 (proven r6-r12)
static __device__ __forceinline__ float qsum4(float z) {
    int p1 = __builtin_amdgcn_update_dpp(0, __builtin_bit_cast(int, z),
                                         0xB1, 0xF, 0xF, true);
    float s1 = z + __builtin_bit_cast(float, p1);
    int p2 = __builtin_amdgcn_update_dpp(0, __builtin_bit_cast(int, s1),
                                         0x4E, 0xF, 0xF, true);
    return s1 + __builtin_bit_cast(float, p2);
}
static __device__ __forceinline__ float sig(float z) {
    return 1.0f / (1.0f + __expf(-z));
}

// ---------------- prep kernel ----------------------------------------------
// producer combined column: K = [conv-x(64) ; U1(100) ; pad(28)] -> 192
static __device__ __forceinline__ _Float16 pwv(const float* __restrict__ W,
                                               const float* __restrict__ U,
                                               int c, int k) {
    float v = (k < FF) ? W[k * G4 + c] : (k < FF + HH ? U[(k - FF) * G4 + c] : 0.0f);
    return (_Float16)v;
}
// consumer combined column: K = [W2(100); pad12 ; U2(100); pad12] -> 224
static __device__ __forceinline__ _Float16 cwv2(const float* __restrict__ W,
                                                const float* __restrict__ U,
                                                int c, int k) {
    if (k < 112) return (k < HH) ? (_Float16)W[k * G4 + c] : (_Float16)0.0f;
    const int kk = k - 112;
    return (kk < HH) ? (_Float16)U[kk * G4 + c] : (_Float16)0.0f;
}

__global__ void prep_weights(const float* __restrict__ w1, const float* __restrict__ u1,
                             const float* __restrict__ w2, const float* __restrict__ u2,
                             h2* __restrict__ ws)
{
    const int idx = blockIdx.x * 256 + threadIdx.x;
    if (idx >= NPH2 + NCH2) return;
    _Float16 lo, hi;
    if (idx < NPH2) {
        const int rt = idx / 96, r = idx % 96;
        const int q = r >> 2, g = r & 3;
        const int p = rt >> 2, sq = rt & 3;
        const int c = g * HH + p;
        const int k = sq * 48 + 2 * q;
        lo = pwv(w1, u1, c, k); hi = pwv(w1, u1, c, k + 1);
    } else {
        const int j = idx - NPH2;
        const int rt = j / 112, r = j % 112;
        const int i = r >> 2, g = r & 3;
        const int p = rt >> 2, sq = rt & 3;
        const int c = g * HH + p;
        const int k = 56 * sq + 2 * i;
        lo = cwv2(w2, u2, c, k); hi = cwv2(w2, u2, c, k + 1);
    }
    ws[idx] = h2{lo, hi};
}

// ---------------- main kernel ----------------------------------------------
__global__ __launch_bounds__(512, 2)
void fused_lstm_kernel(const float* __restrict__ s,       // [B,T]
                       const float* __restrict__ conv_w,  // [2,1,F]
                       const float* __restrict__ conv_b,  // [F]
                       const float* __restrict__ b1,
                       const float* __restrict__ b2,
                       const float* __restrict__ dw, const float* __restrict__ db,
                       h2* __restrict__ wpk,              // packed weights + flags + ring
                       float* __restrict__ out)           // [B,3]
{
    const int tid  = threadIdx.x;
    const int bb   = blockIdx.x;
    const int b    = bb & (NB - 1);
    const bool prod = bb < NB;

    int* pflag = (int*)(wpk + WS_FLAGS) + b;
    int* aflag = (int*)(wpk + WS_FLAGS) + 128 + b;
    unsigned* ring = (unsigned*)(wpk + WS_RING) + (size_t)b * (RINGC * CHUNK_DW);

    __shared__ float s_buf[TT];                        // producer only
    __shared__ __align__(16) _Float16 X1[2 * K1];      // producer operand ring
    __shared__ __align__(16) _Float16 CB[CHK * QC];    // consumer staged chunk
    __shared__ __align__(16) _Float16 HR[2 * QC];      // consumer h2 ring

    if (prod) {
        for (int i = tid; i < TT; i += 512) s_buf[i] = s[(size_t)b * TT + i];
        if (tid < 2 * K1) X1[tid] = (_Float16)0.0f;    // pads stay 0 forever
    } else {
        if (tid < CHK * 6) {                           // zero CB pad dwords [50,56)/row
            const int row = tid / 6, ii = 50 + tid % 6;
            ((unsigned*)CB)[row * 56 + ii] = 0u;
        }
        if (tid < QC) ((unsigned*)HR)[tid] = 0u;       // 2*112 halves = 112 dwords
    }
    __syncthreads();                                   // (A)

    if (prod) {
        // ================= PRODUCER block: conv + LSTM1 =================
        if (tid < 448) {
            const int rt = tid;
            const int active = rt < 400;
            const int lrt = active ? rt : 0;
            const int p = lrt >> 2, sq = lrt & 3;
            const int cA = p, cBi = HH + p, cC = 2 * HH + p, cD = 3 * HH + p;
            const int kb = sq * 48;

            const float4* gptr = (const float4*)(wpk + (size_t)lrt * 96);
            L24(DW4)
            L24(LPK)
            const float bA = b1[cA], bB = b1[cBi], bC = b1[cC], bD = b1[cD];
            __syncthreads();                           // (B)

            float c = 0.0f;
            for (int t = 0; t < TP; ++t) {
                if ((t & 63) == 0) {                   // chunk start: ring credit
                    const int k = t >> 6;
                    if (tid == 0 && k >= RINGC) {
                        int g = 0;
                        while (__hip_atomic_load(aflag, __ATOMIC_ACQUIRE,
                                                 __HIP_MEMORY_SCOPE_AGENT) < k - (RINGC - 1)
                               && g < 50000000) { ++g; __builtin_amdgcn_s_sleep(8); }
                    }
                    __syncthreads();
                }
                if (active) {
                    _Float16* cur = X1 + (t & 1) * K1;
                    _Float16* nx1 = X1 + ((t & 1) ^ 1) * K1;
                    float zA0 = 0.f, zA1 = 0.f, zB0 = 0.f, zB1 = 0.f;
                    float zC0 = 0.f, zC1 = 0.f, zD0 = 0.f, zD1 = 0.f;
                    const float4* vb = (const float4*)(cur + kb);
                    DOTP(0, 0, 1, 2, 3)     DOTP(1, 4, 5, 6, 7)
                    DOTP(2, 8, 9, 10, 11)   DOTP(3, 12, 13, 14, 15)
                    DOTP(4, 16, 17, 18, 19) DOTP(5, 20, 21, 22, 23)
                    const float zi = qsum4(zA0 + zA1) + bA;
                    const float zf = qsum4(zB0 + zB1) + bB;
                    const float zg = qsum4(zC0 + zC1) + bC;
                    const float zo = qsum4(zD0 + zD1) + bD;
                    c = fmaf(sig(zf), c, sig(zi) * fmaxf(zg, 0.f));
                    const float h = sig(zo) * fmaxf(c, 0.f);
                    if (sq == 0) {
                        const _Float16 hq = (_Float16)h;
                        nx1[FF + p] = hq;              // h1 for LSTM1(t+1)
                        // pack (p even | p+1) and device-scope store to ring
                        const unsigned hb = (unsigned)__builtin_bit_cast(unsigned short, hq);
                        const unsigned prt =
                            (unsigned)__builtin_amdgcn_ds_swizzle((int)hb, 0x101F) & 0xFFFFu;
                        if (!(p & 1)) {
                            const unsigned dwv = hb | (prt << 16);
                            __hip_atomic_store(ring + ((t >> 6) & 3) * CHUNK_DW
                                                    + (t & 63) * 50 + (p >> 1),
                                               dwv, __ATOMIC_RELAXED,
                                               __HIP_MEMORY_SCOPE_AGENT);
                        }
                    }
                    if (((t & 63) == 63) || (t == TP - 1))
                        asm volatile("s_waitcnt vmcnt(0)" ::: "memory");
                }
                __syncthreads();                       // (C) one per step
                if (tid == 0 && (((t & 63) == 63) || (t == TP - 1)))
                    __hip_atomic_fetch_add(pflag, 1, __ATOMIC_RELEASE,
                                           __HIP_MEMORY_SCOPE_AGENT);
            }
        } else {
            // conv wave: threads 448-511, one filter each
            const int f = tid - 448;
            const float cv0 = conv_w[f], cv1 = conv_w[FF + f], cb0 = conv_b[f];
            X1[f] = (_Float16)fmaxf(fmaf(s_buf[0], cv0, fmaf(s_buf[1], cv1, cb0)), 0.f);
            __syncthreads();                           // (B)
            for (int t = 0; t < TP; ++t) {
                if ((t & 63) == 0) __syncthreads();    // chunk-start companion
                if (t + 1 < TP) {
                    _Float16* nx1 = X1 + ((t & 1) ^ 1) * K1;
                    nx1[f] = (_Float16)fmaxf(
                        fmaf(s_buf[t + 1], cv0, fmaf(s_buf[t + 2], cv1, cb0)), 0.f);
                }
                __syncthreads();                       // (C)
            }
        }
    } else {
        // ================= CONSUMER block: LSTM2 + dense + softmax ==========
        if (tid < 448) {
            const int rt = tid;
            const int active = rt < 400;
            const int lrt = active ? rt : 0;
            const int p = lrt >> 2, sq = lrt & 3;
            const int cA = p, cBi = HH + p, cC = 2 * HH + p, cD = 3 * HH + p;

            const float4* gptr = (const float4*)(wpk + NPH2 + (size_t)lrt * 112);
            L28(DW4)
            L28(LPK)
            const float bA = b2[cA], bB = b2[cBi], bC = b2[cC], bD = b2[cD];
            __syncthreads();                           // (B)

            float c = 0.0f;
            for (int k = 0; k < NCHUNK; ++k) {
                if (tid == 0) {                        // wait for producer chunk k
                    int g = 0;
                    while (__hip_atomic_load(pflag, __ATOMIC_ACQUIRE,
                                             __HIP_MEMORY_SCOPE_AGENT) < k + 1
                           && g < 50000000) { ++g; __builtin_amdgcn_s_sleep(8); }
                }
                __syncthreads();                       // chunk ready
                const int csz = (TP - (k << 6) < CHK) ? (TP - (k << 6)) : CHK;
                unsigned* gsrc = ring + (k & 3) * CHUNK_DW;
                for (int d = tid; d < csz * 50; d += 448)
                    ((unsigned*)CB)[(d / 50) * 56 + (d % 50)] =
                        __hip_atomic_load(gsrc + d, __ATOMIC_RELAXED,
                                          __HIP_MEMORY_SCOPE_AGENT);
                __syncthreads();                       // staged
                if (tid == 0)
                    __hip_atomic_fetch_add(aflag, 1, __ATOMIC_RELAXED,
                                           __HIP_MEMORY_SCOPE_AGENT);
                for (int lt = 0; lt < csz; ++lt) {
                    const int t = (k << 6) + lt;
                    if (active) {
                        const _Float16* ob = (sq < 2)
                            ? (CB + lt * QC + sq * 56)
                            : (HR + (t & 1) * QC + (sq - 2) * 56);
                        float zA0 = 0.f, zA1 = 0.f, zB0 = 0.f, zB1 = 0.f;
                        float zC0 = 0.f, zC1 = 0.f, zD0 = 0.f, zD1 = 0.f;
                        const float4* vb = (const float4*)ob;
                        DOTP(0, 0, 1, 2, 3)     DOTP(1, 4, 5, 6, 7)
                        DOTP(2, 8, 9, 10, 11)   DOTP(3, 12, 13, 14, 15)
                        DOTP(4, 16, 17, 18, 19) DOTP(5, 20, 21, 22, 23)
                        DOTP(6, 24, 25, 26, 27)
                        const float zi = qsum4(zA0 + zA1) + bA;
                        const float zf = qsum4(zB0 + zB1) + bB;
                        const float zg = qsum4(zC0 + zC1) + bC;
                        const float zo = qsum4(zD0 + zD1) + bD;
                        c = fmaf(sig(zf), c, sig(zi) * fmaxf(zg, 0.f));
                        const float h = sig(zo) * fmaxf(c, 0.f);
                        if (sq == 0)
                            HR[((t & 1) ^ 1) * QC + p] = (_Float16)h;
                    }
                    __syncthreads();                   // (C)
                }
            }

            // final h2(t=2046) was written into slot ((2046&1)^1)=1
            if (rt == 0) {
                float l[3];
#pragma unroll
                for (int a = 0; a < 3; ++a) {
                    float acc = db[a];
                    for (int j = 0; j < HH; ++j)
                        acc = fmaf((float)HR[QC + j], dw[j * 3 + a], acc);
                    l[a] = acc;
                }
                const float m = fmaxf(l[0], fmaxf(l[1], l[2]));
                const float e0 = __expf(l[0] - m), e1 = __expf(l[1] - m), e2 = __expf(l[2] - m);
                const float inv = 1.0f / (e0 + e1 + e2);
                out[b * 3 + 0] = e0 * inv;
                out[b * 3 + 1] = e1 * inv;
                out[b * 3 + 2] = e2 * inv;
            }
        } else {
            // threads 448-511: barrier companions
            __syncthreads();                           // (B)
            for (int k = 0; k < NCHUNK; ++k) {
                __syncthreads();                       // chunk ready
                const int csz = (TP - (k << 6) < CHK) ? (TP - (k << 6)) : CHK;
                __syncthreads();                       // staged
                for (int lt = 0; lt < csz; ++lt)
                    __syncthreads();                   // (C)
            }
        }
    }
}

// ---------------- launch ----------------------------------------------------
extern "C" void kernel_launch(void* const* d_in, const int* in_sizes, int n_in,
                              void* d_out, int out_size, void* d_ws, size_t ws_size,
                              hipStream_t stream) {
    const float* s      = (const float*)d_in[0];
    const float* conv_w = (const float*)d_in[1];
    const float* conv_b = (const float*)d_in[2];
    const float* w1     = (const float*)d_in[3];
    const float* u1     = (const float*)d_in[4];
    const float* b1     = (const float*)d_in[5];
    const float* w2     = (const float*)d_in[6];
    const float* u2     = (const float*)d_in[7];
    const float* b2     = (const float*)d_in[8];
    const float* dw     = (const float*)d_in[9];
    const float* db     = (const float*)d_in[10];

    h2* ws = (h2*)d_ws;
    hipMemsetAsync((void*)((int*)(ws + WS_FLAGS)), 0, 256 * sizeof(int), stream);
    const int nh2 = NPH2 + NCH2;
    prep_weights<<<(nh2 + 255) / 256, 256, 0, stream>>>(w1, u1, w2, u2, ws);
    fused_lstm_kernel<<<256, 512, 0, stream>>>(
        s, conv_w, conv_b, b1, b2, dw, db, ws, (float*)d_out);
}